// Round 18
// baseline (94.530 us; speedup 1.0000x reference)
//
#include <hip/hip_runtime.h>
#include <math.h>

#define NP 128       // patches per side
#define NB 32        // batch (light dirs)

typedef float vf4 __attribute__((ext_vector_type(4)));  // native 16B vector

// ---------------------------------------------------------------------------
// R15 structure (b-major, NT stores, hoisted v[3]) + __launch_bounds__(256,8):
// force <=64 VGPR so 8 waves/SIMD can be resident -> deeper store pipeline.
// Single-variable occupancy probe vs R15 (88.2us).
// ---------------------------------------------------------------------------
__global__ __launch_bounds__(256, 8) void fused_relight(
    const float* __restrict__ ld,   // [32][2]
    const float* __restrict__ w1,   // [p][8][2]
    const float* __restrict__ b1,   // [p][8]
    const float* __restrict__ w2,   // [p][8][8]
    const float* __restrict__ b2,   // [p][8]
    const float* __restrict__ w3,   // [p][8][8]
    const float* __restrict__ b3,   // [p][8]
    const float* __restrict__ wo,   // [p][3][8]
    const float* __restrict__ bo,   // [p][3]
    float* __restrict__ out)        // [32][1024][1024][3] f32
{
    int bid = blockIdx.x;        // 0 .. 4095
    int b  = bid >> 7;           // light index   (b-major)
    int ph = bid & 127;          // patch row -> xcd = ph % 8
    int t  = threadIdx.x;        // 0 .. 255

    __shared__ float cl[NP * 3];  // 384 floats

    if (t < NP) {
        int p = ph * NP + t;     // patch id
        float x0 = ld[2 * b + 0];
        float x1 = ld[2 * b + 1];

        float h[8], g[8];
        {   // layer 1: 2 -> 8
            const float* W  = w1 + (size_t)p * 16;
            const float* Bv = b1 + (size_t)p * 8;
#pragma unroll
            for (int o = 0; o < 8; ++o) {
                float s = fmaf(W[2 * o + 0], x0, fmaf(W[2 * o + 1], x1, Bv[o]));
                h[o] = fmaxf(0.f, s);
            }
        }
        {   // layer 2: 8 -> 8
            const float* W  = w2 + (size_t)p * 64;
            const float* Bv = b2 + (size_t)p * 8;
#pragma unroll
            for (int o = 0; o < 8; ++o) {
                float s = Bv[o];
#pragma unroll
                for (int i = 0; i < 8; ++i) s = fmaf(W[8 * o + i], h[i], s);
                g[o] = fmaxf(0.f, s);
            }
        }
        {   // layer 3: 8 -> 8
            const float* W  = w3 + (size_t)p * 64;
            const float* Bv = b3 + (size_t)p * 8;
#pragma unroll
            for (int o = 0; o < 8; ++o) {
                float s = Bv[o];
#pragma unroll
                for (int i = 0; i < 8; ++i) s = fmaf(W[8 * o + i], g[i], s);
                h[o] = fmaxf(0.f, s);
            }
        }
        {   // out layer: 8 -> 3, sigmoid -> LDS
            const float* W  = wo + (size_t)p * 24;
            const float* Bv = bo + (size_t)p * 3;
#pragma unroll
            for (int c = 0; c < 3; ++c) {
                float s = Bv[c];
#pragma unroll
                for (int i = 0; i < 8; ++i) s = fmaf(W[8 * c + i], h[i], s);
                cl[t * 3 + c] = 1.f / (1.f + expf(-s));
            }
        }
    }
    __syncthreads();

    // Phase 2: compute this thread's 3 chunk values once.
    vf4 v[3];
#pragma unroll
    for (int j = 0; j < 3; ++j) {
        int ct = j * 256 + t;         // 0..767
        int pw = ct / 6;
        int s  = ct % 3;

        float c0 = cl[pw * 3 + 0];
        float c1 = cl[pw * 3 + 1];
        float c2 = cl[pw * 3 + 2];
        float ca = (s == 0) ? c0 : ((s == 1) ? c1 : c2);
        float cb = (s == 0) ? c1 : ((s == 1) ? c2 : c0);
        float cc = (s == 0) ? c2 : ((s == 1) ? c0 : c1);

        v[j].x = ca; v[j].y = cb; v[j].z = cc; v[j].w = ca;
    }

    // NT stores, same per-wave address sequence as R15.
    vf4* op = (vf4*)out + (size_t)b * 786432 + (size_t)ph * 6144;
#pragma unroll
    for (int row = 0; row < 8; ++row) {
        __builtin_nontemporal_store(v[0], &op[row * 768 + t]);
        __builtin_nontemporal_store(v[1], &op[row * 768 + 256 + t]);
        __builtin_nontemporal_store(v[2], &op[row * 768 + 512 + t]);
    }
}

extern "C" void kernel_launch(void* const* d_in, const int* in_sizes, int n_in,
                              void* d_out, int out_size, void* d_ws, size_t ws_size,
                              hipStream_t stream) {
    const float* ld = (const float*)d_in[0];
    const float* w1 = (const float*)d_in[1];
    const float* b1 = (const float*)d_in[2];
    const float* w2 = (const float*)d_in[3];
    const float* b2 = (const float*)d_in[4];
    const float* w3 = (const float*)d_in[5];
    const float* b3 = (const float*)d_in[6];
    const float* wo = (const float*)d_in[7];
    const float* bo = (const float*)d_in[8];

    float* out = (float*)d_out;

    fused_relight<<<dim3(NB * NP), dim3(256), 0, stream>>>(
        ld, w1, b1, w2, b2, w3, b3, wo, bo, out);
}

// Round 19
// 90.294 us; speedup vs baseline: 1.0469x; 1.0469x over previous
//
#include <hip/hip_runtime.h>
#include <math.h>

#define NP 128       // patches per side
#define NB 32        // batch (light dirs)

typedef float vf4 __attribute__((ext_vector_type(4)));  // native 16B vector

// ---------------------------------------------------------------------------
// Block = (b, ph-pair): 2048 blocks, xcd = bid%8 = phc%8 (weights XCD-local).
//  phase 1: ALL 256 threads run one MLP each (2 patch rows: r = t>>7,
//           col = t&127) -> cl[2][384].
//  phase 2: 192 KB contiguous slab (16 image rows); per row-group r: hoisted
//           v[3] from cl[r], 24 NT float4 stores (proven R13/R15 writer).
// ---------------------------------------------------------------------------
__global__ __launch_bounds__(256) void fused_relight2(
    const float* __restrict__ ld,   // [32][2]
    const float* __restrict__ w1,   // [p][8][2]
    const float* __restrict__ b1,   // [p][8]
    const float* __restrict__ w2,   // [p][8][8]
    const float* __restrict__ b2,   // [p][8]
    const float* __restrict__ w3,   // [p][8][8]
    const float* __restrict__ b3,   // [p][8]
    const float* __restrict__ wo,   // [p][3][8]
    const float* __restrict__ bo,   // [p][3]
    float* __restrict__ out)        // [32][1024][1024][3] f32
{
    int bid = blockIdx.x;        // 0 .. 2047
    int b   = bid >> 6;          // light index (b-major)
    int phc = bid & 63;          // patch-row pair -> xcd = phc % 8
    int t   = threadIdx.x;       // 0 .. 255

    __shared__ float cl[2][NP * 3];  // 2 x 384 floats

    {
        int r   = t >> 7;            // 0..1 local patch row
        int col = t & 127;           // patch col
        int p = (phc * 2 + r) * NP + col;   // patch id

        float x0 = ld[2 * b + 0];
        float x1 = ld[2 * b + 1];

        float h[8], g[8];
        {   // layer 1: 2 -> 8
            const float* W  = w1 + (size_t)p * 16;
            const float* Bv = b1 + (size_t)p * 8;
#pragma unroll
            for (int o = 0; o < 8; ++o) {
                float s = fmaf(W[2 * o + 0], x0, fmaf(W[2 * o + 1], x1, Bv[o]));
                h[o] = fmaxf(0.f, s);
            }
        }
        {   // layer 2: 8 -> 8
            const float* W  = w2 + (size_t)p * 64;
            const float* Bv = b2 + (size_t)p * 8;
#pragma unroll
            for (int o = 0; o < 8; ++o) {
                float s = Bv[o];
#pragma unroll
                for (int i = 0; i < 8; ++i) s = fmaf(W[8 * o + i], h[i], s);
                g[o] = fmaxf(0.f, s);
            }
        }
        {   // layer 3: 8 -> 8
            const float* W  = w3 + (size_t)p * 64;
            const float* Bv = b3 + (size_t)p * 8;
#pragma unroll
            for (int o = 0; o < 8; ++o) {
                float s = Bv[o];
#pragma unroll
                for (int i = 0; i < 8; ++i) s = fmaf(W[8 * o + i], g[i], s);
                h[o] = fmaxf(0.f, s);
            }
        }
        {   // out layer: 8 -> 3, sigmoid -> LDS
            const float* W  = wo + (size_t)p * 24;
            const float* Bv = bo + (size_t)p * 3;
#pragma unroll
            for (int c = 0; c < 3; ++c) {
                float s = Bv[c];
#pragma unroll
                for (int i = 0; i < 8; ++i) s = fmaf(W[8 * c + i], h[i], s);
                cl[r][col * 3 + c] = 1.f / (1.f + expf(-s));
            }
        }
    }
    __syncthreads();

    // Phase 2: 16 rows x 768 vf4 = 12288 chunks, 192 KB contiguous.
    // Row-group rg uses cl[rg]; chunk ct: pw = ct/6, s = ct%3.
    vf4* op = (vf4*)out + (size_t)b * 786432 + (size_t)phc * 12288;

#pragma unroll
    for (int rg = 0; rg < 2; ++rg) {
        vf4 v[3];
#pragma unroll
        for (int j = 0; j < 3; ++j) {
            int ct = j * 256 + t;         // 0..767
            int pw = ct / 6;
            int s  = ct % 3;

            float c0 = cl[rg][pw * 3 + 0];
            float c1 = cl[rg][pw * 3 + 1];
            float c2 = cl[rg][pw * 3 + 2];
            float ca = (s == 0) ? c0 : ((s == 1) ? c1 : c2);
            float cb = (s == 0) ? c1 : ((s == 1) ? c2 : c0);
            float cc = (s == 0) ? c2 : ((s == 1) ? c0 : c1);

            v[j].x = ca; v[j].y = cb; v[j].z = cc; v[j].w = ca;
        }

        vf4* gp = op + (size_t)rg * 6144;   // 8 rows per group
#pragma unroll
        for (int row = 0; row < 8; ++row) {
            __builtin_nontemporal_store(v[0], &gp[row * 768 + t]);
            __builtin_nontemporal_store(v[1], &gp[row * 768 + 256 + t]);
            __builtin_nontemporal_store(v[2], &gp[row * 768 + 512 + t]);
        }
    }
}

extern "C" void kernel_launch(void* const* d_in, const int* in_sizes, int n_in,
                              void* d_out, int out_size, void* d_ws, size_t ws_size,
                              hipStream_t stream) {
    const float* ld = (const float*)d_in[0];
    const float* w1 = (const float*)d_in[1];
    const float* b1 = (const float*)d_in[2];
    const float* w2 = (const float*)d_in[3];
    const float* b2 = (const float*)d_in[4];
    const float* w3 = (const float*)d_in[5];
    const float* b3 = (const float*)d_in[6];
    const float* wo = (const float*)d_in[7];
    const float* bo = (const float*)d_in[8];

    float* out = (float*)d_out;

    fused_relight2<<<dim3(NB * (NP / 2)), dim3(256), 0, stream>>>(
        ld, w1, b1, w2, b2, w3, b3, wo, bo, out);
}